// Round 4
// baseline (574.471 us; speedup 1.0000x reference)
//
#include <hip/hip_runtime.h>
#include <hip/hip_cooperative_groups.h>
#include <math.h>

namespace cg = cooperative_groups;

#define NROWS 4096
#define NCOLS 16384
#define NGRP  512                   // NCOLS / 32
#define TOTAL_ELEMS (67108864ULL)   // NROWS * NCOLS
#define TOTAL4      (16777216ULL)   // TOTAL_ELEMS / 4
#define GRID_BLOCKS 1024
#define BLOCK 256
#define STRIDE ((size_t)GRID_BLOCKS * BLOCK)   // 262144 ≡ 0 mod 4096

typedef float nfloat4 __attribute__((ext_vector_type(4)));  // native vec for nt-store

// Key invariant: stride is a multiple of 4096 float4s (one row), so each
// thread's group index g = (tid0 & 4095) >> 3 is LOOP-INVARIANT.

__global__ void init_kernel(unsigned int* __restrict__ gmax) {
    gmax[threadIdx.x] = 0u;   // 512 threads, 1 block (gmax lives in d_ws)
}

__device__ __forceinline__ float quant1(float a, float s, float inv, float ee) {
    float r  = fminf(fabsf(a) * inv, 1.f);        // clip(|w|/s,0,1) — exact mul
    float sh = fminf(fmaxf(r + ee, 0.f), 1.f);    // clip(+eps_eff, 0, 1)
    float mq = rintf(sh * 8.f) * 0.125f;          // round-half-even = np.round
    float q  = copysignf(s * mq, a);
    return (a == 0.f) ? 0.f : q;                  // jnp.sign(0) == 0
}

// Single cooperative kernel: phase A = per-group max|w| (private max →
// 8-lane shfl reduce → LDS atomic → global atomic), grid.sync(), phase B =
// per-thread group-param derivation + elementwise quant. Weight (256 MiB)
// exactly fits the Infinity Cache, so phase B's re-read is ~all L3 hits;
// nt-stores keep the output stream from evicting it.
__global__ void __launch_bounds__(BLOCK, 4)
fused_kernel(const float4* __restrict__ w,
             const float* __restrict__ eps_param,
             const float* __restrict__ delta,
             unsigned int* __restrict__ gmax,
             float* __restrict__ tail,
             float4* __restrict__ out) {
    __shared__ unsigned int smax[NGRP];
    for (int i = threadIdx.x; i < NGRP; i += BLOCK) smax[i] = 0u;
    __syncthreads();

    const size_t tid0 = (size_t)blockIdx.x * BLOCK + threadIdx.x;
    const int g = (int)((tid0 & 4095) >> 3);                // loop-invariant

    // ---- phase A: max|w| (64 iters/thread, 2 loads in flight) ----
    float m0 = 0.f, m1 = 0.f;
    for (size_t i = tid0; i < TOTAL4; i += 2 * STRIDE) {
        float4 a = w[i];
        float4 b = w[i + STRIDE];
        m0 = fmaxf(m0, fmaxf(fmaxf(fabsf(a.x), fabsf(a.y)),
                             fmaxf(fabsf(a.z), fabsf(a.w))));
        m1 = fmaxf(m1, fmaxf(fmaxf(fabsf(b.x), fabsf(b.y)),
                             fmaxf(fabsf(b.z), fabsf(b.w))));
    }
    float m = fmaxf(m0, m1);
    // 8 consecutive lanes share g (blocks are 256-aligned in tid)
    m = fmaxf(m, __shfl_xor(m, 1, 64));
    m = fmaxf(m, __shfl_xor(m, 2, 64));
    m = fmaxf(m, __shfl_xor(m, 4, 64));
    if ((threadIdx.x & 7) == 0)
        atomicMax(&smax[g], __float_as_uint(m));
    __syncthreads();
    for (int j = threadIdx.x; j < NGRP; j += BLOCK)
        if (smax[j]) atomicMax(&gmax[j], smax[j]);   // device-scope

    cg::this_grid().sync();

    // ---- phase B: derive group params, write tail, quantize ----
    unsigned mb = __hip_atomic_load(&gmax[g], __ATOMIC_RELAXED,
                                    __HIP_MEMORY_SCOPE_AGENT);
    float ma = __uint_as_float(mb);
    float e = 0.f;
    if (ma > 0.f) {
        int ex;
        (void)frexpf(ma, &ex);      // ma = m * 2^ex, m in [0.5, 1)
        e = (float)(ex - 1);        // floor(log2(ma)) exactly
    }
    float eps = 0.5f * tanhf(eps_param[g]);
    float ee  = fminf(fmaxf(eps + delta[g], -0.5f), 0.5f);
    const int   ei  = (int)e;
    const float s   = __uint_as_float((unsigned)(ei + 127) << 23);  // 2^e
    const float inv = __uint_as_float((unsigned)(127 - ei) << 23);  // 2^-e

    // one writer per group lives in the first 16 blocks
    if (tid0 < 4096 && (tid0 & 7) == 0) {
        tail[g]        = ee;    // output: eps_eff
        tail[NGRP + g] = e;     // output: e_base
    }

    // Descending sweep: freshest L3 lines first (phase A ended at high i).
    for (size_t ii = 0; ii < TOTAL4; ii += 2 * STRIDE) {
        size_t i = (TOTAL4 - 2 * STRIDE - ii) + tid0;
        float4 a = w[i];
        float4 b = w[i + STRIDE];
        nfloat4 oa, ob;
        oa.x = quant1(a.x, s, inv, ee);
        oa.y = quant1(a.y, s, inv, ee);
        oa.z = quant1(a.z, s, inv, ee);
        oa.w = quant1(a.w, s, inv, ee);
        __builtin_nontemporal_store(oa, (nfloat4*)&out[i]);
        ob.x = quant1(b.x, s, inv, ee);
        ob.y = quant1(b.y, s, inv, ee);
        ob.z = quant1(b.z, s, inv, ee);
        ob.w = quant1(b.w, s, inv, ee);
        __builtin_nontemporal_store(ob, (nfloat4*)&out[i + STRIDE]);
    }
}

extern "C" void kernel_launch(void* const* d_in, const int* in_sizes, int n_in,
                              void* d_out, int out_size, void* d_ws, size_t ws_size,
                              hipStream_t stream) {
    const float4* w4       = (const float4*)d_in[0];
    const float* eps_param = (const float*)d_in[1];
    const float* delta     = (const float*)d_in[2];
    float* out  = (float*)d_out;
    float* tail = out + TOTAL_ELEMS;            // 1024 floats: eps_eff + e_base
    unsigned int* gmax = (unsigned int*)d_ws;   // 512 uints of scratch
    float4* out4 = (float4*)out;

    init_kernel<<<1, NGRP, 0, stream>>>(gmax);

    void* args[] = { (void*)&w4, (void*)&eps_param, (void*)&delta,
                     (void*)&gmax, (void*)&tail, (void*)&out4 };
    hipLaunchCooperativeKernel((const void*)fused_kernel,
                               dim3(GRID_BLOCKS), dim3(BLOCK),
                               args, 0, stream);
}